// Round 8
// baseline (839.819 us; speedup 1.0000x reference)
//
#include <hip/hip_runtime.h>
#include <hip/hip_fp16.h>
#include <math.h>

#define S_TOK 8192
#define DMODEL 1024
#define HDIM 4096
#define NEXP 8
#define KTOP2 2
#define CAP 2560
#define SK (S_TOK*KTOP2)

typedef _Float16 f16;
typedef _Float16 f16x8 __attribute__((ext_vector_type(8)));
typedef float f32x4 __attribute__((ext_vector_type(4)));

typedef const __attribute__((address_space(1))) void* gas_cp;
typedef __attribute__((address_space(3))) void* las_p;

__device__ __forceinline__ void gload16(const void* g, void* l) {
  __builtin_amdgcn_global_load_lds((gas_cp)g, (las_p)l, 16, 0, 0);
}

// ---------------- ws layout (bytes) ----------------
static const size_t ZERO_OFF  = 0;          // 4096 zeroed every call
static const size_t IMP_OFF   = 4096;
static const size_t CNT_OFF   = 4160;
static const size_t NSEL_OFF  = 4224;
static const size_t PROBS_OFF = 8192;
static const size_t TOPKI_OFF = 270336;
static const size_t TOPKV_OFF = 335872;
static const size_t LISTT_OFF = 401408;
static const size_t LISTW_OFF = 663552;
static const size_t LISTF_OFF = 925696;     // dead after select -> reused for tokmap
static const size_t SELT_OFF  = 1187840;
static const size_t SELW_OFF  = 1269760;
static const size_t XF16_OFF  = 1351680;                                  // S*D f16 = 16MB
static const size_t W1TA_OFF  = 18128896;                                 // 8*H*D f16 = 64MB
static const size_t W2TA_OFF  = W1TA_OFF + (size_t)NEXP*HDIM*DMODEL*2;
static const size_t HA_OFF    = W2TA_OFF + (size_t)NEXP*DMODEL*HDIM*2;    // 8*CAP*H f16 = 160MB
static const size_t YE_OFF    = XF16_OFF;   // 40MB aliased over xf16/w1t (dead by gemm2)
static const size_t TOKMAP_OFF = LISTF_OFF;

// ---------------- fast erf-based gelu (A&S 7.1.26, |err|<1.5e-7) ----------------
__device__ __forceinline__ float fast_gelu(float v) {
  float av = fabsf(v);
  float z  = av * 0.70710678118654752f;
  float tt = __builtin_amdgcn_rcpf(1.0f + 0.3275911f*z);
  float poly = tt*(0.254829592f + tt*(-0.284496736f + tt*(1.421413741f + tt*(-1.453152027f + tt*1.061405429f))));
  float ee = 1.0f - poly*__expf(-z*z);       // erf(z) for z>=0
  return 0.5f*(v + v*copysignf(ee, v));      // 0.5*v*(1+erf(v/sqrt2))
}

// ---------------- x -> f16 ----------------
__global__ __launch_bounds__(256) void cvt_x_kernel(const float* __restrict__ x, f16* __restrict__ xf) {
  size_t i = (size_t)blockIdx.x*256 + threadIdx.x;
  const float4* xv = (const float4*)x;
  float4 a = xv[2*i], b = xv[2*i+1];
  union { f16 h[8]; uint4 u; } p;
  p.h[0]=(f16)a.x; p.h[1]=(f16)a.y; p.h[2]=(f16)a.z; p.h[3]=(f16)a.w;
  p.h[4]=(f16)b.x; p.h[5]=(f16)b.y; p.h[6]=(f16)b.z; p.h[7]=(f16)b.w;
  ((uint4*)xf)[i] = p.u;
}

// ---------------- gate ----------------
__global__ __launch_bounds__(256) void gate_kernel(const float* __restrict__ x, const float* __restrict__ Wg,
                                                   float* __restrict__ probs, int* __restrict__ tki,
                                                   float* __restrict__ tkv) {
  int lane = threadIdx.x & 63;
  int t = blockIdx.x*4 + (threadIdx.x >> 6);
  const float* xr = x + (size_t)t*DMODEL;
  float p[NEXP];
  #pragma unroll
  for (int e=0;e<NEXP;e++) p[e] = 0.f;
  for (int d = lane; d < DMODEL; d += 64) {
    float xv = xr[d];
    const float4* wg = (const float4*)(Wg + d*NEXP);
    float4 w0 = wg[0], w1 = wg[1];
    p[0] += xv*w0.x; p[1] += xv*w0.y; p[2] += xv*w0.z; p[3] += xv*w0.w;
    p[4] += xv*w1.x; p[5] += xv*w1.y; p[6] += xv*w1.z; p[7] += xv*w1.w;
  }
  #pragma unroll
  for (int off=32; off; off>>=1) {
    #pragma unroll
    for (int e=0;e<NEXP;e++) p[e] += __shfl_xor(p[e], off);
  }
  float mx = p[0];
  #pragma unroll
  for (int e=1;e<NEXP;e++) mx = fmaxf(mx, p[e]);
  float sum = 0.f;
  #pragma unroll
  for (int e=0;e<NEXP;e++) { p[e] = expf(p[e]-mx); sum += p[e]; }
  float inv = 1.f/sum;
  #pragma unroll
  for (int e=0;e<NEXP;e++) p[e] *= inv;
  if (lane == 0) {
    ((float4*)(probs + t*NEXP))[0] = make_float4(p[0],p[1],p[2],p[3]);
    ((float4*)(probs + t*NEXP))[1] = make_float4(p[4],p[5],p[6],p[7]);
    int i1 = 0; float v1 = p[0];
    #pragma unroll
    for (int e=1;e<NEXP;e++) if (p[e] > v1) { v1 = p[e]; i1 = e; }
    int i2 = -1; float v2 = -1.f;
    #pragma unroll
    for (int e=0;e<NEXP;e++) if (e != i1 && p[e] > v2) { v2 = p[e]; i2 = e; }
    tki[t*2] = i1; tki[t*2+1] = i2;
    tkv[t*2] = v1; tkv[t*2+1] = v2;
  }
}

// ---------------- importance ----------------
__global__ __launch_bounds__(256) void imp_kernel(const float* __restrict__ probs, float* __restrict__ imp) {
  int e = blockIdx.x;
  float s = 0.f;
  for (int t = threadIdx.x; t < S_TOK; t += 256) s += probs[t*NEXP + e];
  #pragma unroll
  for (int off=32; off; off>>=1) s += __shfl_xor(s, off);
  __shared__ float red[4];
  if ((threadIdx.x & 63) == 0) red[threadIdx.x>>6] = s;
  __syncthreads();
  if (threadIdx.x == 0) imp[e] = red[0]+red[1]+red[2]+red[3];
}

// ---------------- compact ----------------
__global__ __launch_bounds__(256) void compact_kernel(const int* __restrict__ tki, const float* __restrict__ tkv,
                                                      int* __restrict__ cnt, int* __restrict__ listt,
                                                      float* __restrict__ listw, int* __restrict__ listf) {
  int i = blockIdx.x*256 + threadIdx.x;
  int e = tki[i];
  int p = atomicAdd(&cnt[e], 1);
  listt[e*S_TOK + p] = i >> 1;
  listw[e*S_TOK + p] = tkv[i];
  listf[e*S_TOK + p] = i;
}

// ---------------- capacity selection ----------------
__global__ __launch_bounds__(1024) void select_kernel(const int* __restrict__ listt, const float* __restrict__ listw,
                                                      const int* __restrict__ listf, const int* __restrict__ cnt,
                                                      int* __restrict__ selt, float* __restrict__ selw,
                                                      int* __restrict__ nsel) {
  __shared__ float kw[8192];
  __shared__ unsigned short kf[8192];
  int e = blockIdx.x;
  int n = cnt[e];
  const int* lt = listt + e*S_TOK; const float* lw = listw + e*S_TOK; const int* lf = listf + e*S_TOK;
  int* st = selt + e*CAP; float* sw = selw + e*CAP;
  if (threadIdx.x == 0) nsel[e] = (n < CAP) ? n : CAP;
  if (n <= CAP) {
    for (int i = threadIdx.x; i < CAP; i += 1024) {
      if (i < n) { st[i] = lt[i]; sw[i] = lw[i]; }
      else       { st[i] = -1;    sw[i] = 0.f;  }
    }
  } else {
    for (int i = threadIdx.x; i < n; i += 1024) { kw[i] = lw[i]; kf[i] = (unsigned short)lf[i]; }
    __syncthreads();
    for (int i = threadIdx.x; i < n; i += 1024) {
      float wi = kw[i]; int fi = kf[i];
      int rank = 0;
      for (int j = 0; j < n; ++j) {
        float wj = kw[j];
        rank += (wj > wi) || (wj == wi && (int)kf[j] < fi);
      }
      if (rank < CAP) { st[rank] = lt[i]; sw[rank] = wi; }
    }
  }
}

// ---------------- aux loss ----------------
__global__ void aux_kernel(const float* __restrict__ imp, const int* __restrict__ cnt, float* __restrict__ aux_out) {
  if (threadIdx.x == 0 && blockIdx.x == 0) {
    float a = 0.f;
    #pragma unroll
    for (int e=0;e<NEXP;e++) a += imp[e] * (float)cnt[e];
    *aux_out = a * (8.0f / 67108864.0f);
  }
}

// ---------------- tokmap: token -> (expert,slot) pairs ----------------
__global__ __launch_bounds__(256) void buildmap_kernel(const int* __restrict__ selt, const int* __restrict__ tki,
                                                       int* __restrict__ tokmap) {
  int i = blockIdx.x*256 + threadIdx.x;       // 0 .. E*CAP
  int t = selt[i];
  if (t >= 0) {
    int e = i / CAP;
    int k = (tki[2*t] == e) ? 0 : 1;
    tokmap[2*t + k] = i;
  }
}

// ---------------- combine: out[t] = ye[i0] + ye[i1]  (weights already applied) ----------------
__global__ __launch_bounds__(256) void combine2_kernel(const f16* __restrict__ ye, const int* __restrict__ tokmap,
                                                       float* __restrict__ out) {
  int t = blockIdx.x;
  int c = threadIdx.x * 4;
  int i0 = tokmap[2*t], i1 = tokmap[2*t+1];
  float4 o = {0.f, 0.f, 0.f, 0.f};
  if (i0 >= 0) {
    union { short4 s; f16 h[4]; } v;
    v.s = *(const short4*)(ye + (size_t)i0*DMODEL + c);
    o.x += (float)v.h[0]; o.y += (float)v.h[1]; o.z += (float)v.h[2]; o.w += (float)v.h[3];
  }
  if (i1 >= 0) {
    union { short4 s; f16 h[4]; } v;
    v.s = *(const short4*)(ye + (size_t)i1*DMODEL + c);
    o.x += (float)v.h[0]; o.y += (float)v.h[1]; o.z += (float)v.h[2]; o.w += (float)v.h[3];
  }
  *(float4*)(out + (size_t)t*DMODEL + c) = o;
}

// ---------------- transpose + cvt ----------------
__global__ __launch_bounds__(256) void tcvt_kernel(const float* __restrict__ src0, f16* __restrict__ dst0,
                                                   int R, int C) {
  __shared__ float tile[32][33];
  const float* src = src0 + (size_t)blockIdx.z*R*C;
  f16* dst = dst0 + (size_t)blockIdx.z*R*C;
  int tx = threadIdx.x, ty = threadIdx.y;
  int c0 = blockIdx.x*32, r0 = blockIdx.y*32;
  #pragma unroll
  for (int j=0;j<4;j++)
    tile[ty + 8*j][tx] = src[(size_t)(r0 + ty + 8*j)*C + c0 + tx];
  __syncthreads();
  #pragma unroll
  for (int j=0;j<4;j++)
    dst[(size_t)(c0 + ty + 8*j)*R + r0 + tx] = (f16)tile[tx][ty + 8*j];
}

// ================= GEMM bodies: depth-3 counted-vmcnt pipeline =================
// 128x128 tile, BK=64, 8 waves x (64x32), 3 LDS buffers (96KB -> 1 block/CU).
// Iter kt: stage buf kt+2 (4 gload16/thread), vmcnt(8) (waits ONLY buf kt; the
// 8 loads of bufs kt+1/kt+2 stay in flight across the barrier - T4, m218),
// raw s_barrier (no compiler vmcnt(0) drain), 32 MFMA wrapped in setprio (T5),
// barrier, rotate named buffer pointers (no runtime-indexed arrays, rule #20).
// Epilogue: vmcnt 8 -> 4 -> 0. 8-row XOR swizzle: 0 bank conflicts (r6-verified).
// Hazards: stage target last read 2 iters ago, separated by closing barrier;
// vmcnt-then-barrier publishes all waves' loads before any read.

#define BAR() asm volatile("s_barrier" ::: "memory")
#define VMW(n) asm volatile("s_waitcnt vmcnt(" #n ")" ::: "memory")

#define GEMM8_PREAMBLE() \
  __shared__ __align__(16) f16 As[3][128*64]; \
  __shared__ __align__(16) f16 Bs[3][128*64]; \
  int tid = threadIdx.x; \
  int l = tid & 63; \
  int w = tid >> 6; \
  int wr = w >> 2, wc = w & 3; \
  int fr = l & 15, kq = l >> 4; \
  int srow = tid >> 3; \
  int swz = ((tid & 7) ^ (srow & 7)) * 16; \
  int aoff[4][2], boff[2][2]; \
  _Pragma("unroll") for (int m=0;m<4;m++) _Pragma("unroll") for (int ks=0;ks<2;ks++) \
    aoff[m][ks] = (wr*64 + m*16 + fr)*128 + (((ks*4+kq) ^ (fr&7))*16); \
  _Pragma("unroll") for (int n=0;n<2;n++) _Pragma("unroll") for (int ks=0;ks<2;ks++) \
    boff[n][ks] = (wc*32 + n*16 + fr)*128 + (((ks*4+kq) ^ (fr&7))*16); \
  f32x4 acc[4][2]; \
  _Pragma("unroll") for (int m=0;m<4;m++) _Pragma("unroll") for (int n=0;n<2;n++) \
    acc[m][n] = (f32x4){0.f,0.f,0.f,0.f};

#define GEMM8_STAGE3(Ad, Bd, kt) { int ko = (kt)*128; \
    gload16(sa0 + ko, Ad + tid*16); \
    gload16(sa1 + ko, Ad + 8192 + tid*16); \
    gload16(sb0 + ko, Bd + tid*16); \
    gload16(sb1 + ko, Bd + 8192 + tid*16); }

#define GEMM8_MAINLOOP(KT) { \
  char* cA = (char*)&As[0][0]; char* nA = (char*)&As[1][0]; char* pA = (char*)&As[2][0]; \
  char* cB = (char*)&Bs[0][0]; char* nB = (char*)&Bs[1][0]; char* pB = (char*)&Bs[2][0]; \
  GEMM8_STAGE3(cA, cB, 0); \
  GEMM8_STAGE3(nA, nB, 1); \
  for (int kt = 0; kt < (KT); ++kt) { \
    if (kt + 2 < (KT)) { GEMM8_STAGE3(pA, pB, kt+2); VMW(8); } \
    else if (kt + 1 < (KT)) { VMW(4); } \
    else { VMW(0); } \
    BAR(); \
    __builtin_amdgcn_s_setprio(1); \
    _Pragma("unroll") for (int ks=0; ks<2; ++ks) { \
      f16x8 af[4], bf[2]; \
      _Pragma("unroll") for (int m=0;m<4;m++) af[m] = *(const f16x8*)(cA + aoff[m][ks]); \
      _Pragma("unroll") for (int n=0;n<2;n++) bf[n] = *(const f16x8*)(cB + boff[n][ks]); \
      _Pragma("unroll") for (int m=0;m<4;m++) \
        _Pragma("unroll") for (int n=0;n<2;n++) \
          acc[m][n] = __builtin_amdgcn_mfma_f32_16x16x32_f16(af[m], bf[n], acc[m][n], 0, 0, 0); \
    } \
    __builtin_amdgcn_s_setprio(0); \
    BAR(); \
    char* t0 = cA; cA = nA; nA = pA; pA = t0; \
    char* t1 = cB; cB = nB; nB = pB; pB = t1; \
  } }

// ---------------- GEMM1 fused over experts ----------------
__global__ __launch_bounds__(512, 2) void gemm1_fused(const f16* __restrict__ xf, const f16* __restrict__ w1t_all,
                                                      const int* __restrict__ selt_all, const int* __restrict__ nsel_all,
                                                      f16* __restrict__ hbuf_all, const char* __restrict__ zbuf) {
  int bid = blockIdx.x;
  int wid = (bid & 7)*640 + (bid >> 3);      // XCD-chunked: each XCD = one expert
  int e = wid / 640; int rem = wid - e*640;  // 640 = 20 m-blocks x 32 n-panels
  // supertile order: (mh 0..1) x (sc 0..15) x (lm 0..9) x (ln 0..1)
  int g  = rem / 20;
  int mh = g >> 4, sc = g & 15;
  int lm = (rem % 20) >> 1, ln = rem & 1;
  int m0 = (mh*10 + lm) * 128;
  int n0 = (sc*2 + ln) * 128;
  int nsel = nsel_all[e];
  if (m0 >= nsel) return;
  const int* selt = selt_all + e*CAP;
  const f16* w1t = w1t_all + (size_t)e*HDIM*DMODEL;
  f16* hbuf = hbuf_all + (size_t)e*CAP*HDIM;

  GEMM8_PREAMBLE();

  const char *sa0, *sa1;
  {
    int t0 = selt[m0 + srow];
    int t1 = selt[m0 + 64 + srow];
    sa0 = ((t0 >= 0) ? (const char*)(xf + (size_t)t0*DMODEL) : zbuf) + swz;
    sa1 = ((t1 >= 0) ? (const char*)(xf + (size_t)t1*DMODEL) : zbuf) + swz;
  }
  const char* sb0 = (const char*)(w1t + (size_t)(n0 + srow)*DMODEL) + swz;
  const char* sb1 = (const char*)(w1t + (size_t)(n0 + 64 + srow)*DMODEL) + swz;

  GEMM8_MAINLOOP(DMODEL/64);

  int rowb = m0 + wr*64;
  int colb = n0 + wc*32;
  #pragma unroll
  for (int m=0;m<4;m++) {
    #pragma unroll
    for (int n=0;n<2;n++) {
      #pragma unroll
      for (int r=0;r<4;r++) {
        int row = rowb + m*16 + kq*4 + r;
        int col = colb + n*16 + fr;
        hbuf[(size_t)row*HDIM + col] = (f16)fast_gelu(acc[m][n][r]);
      }
    }
  }
}

// ---------------- GEMM2 fused: ye[e,row] = wg * (h @ W2T), no atomics ----------------
__global__ __launch_bounds__(512, 2) void gemm2_fused(const f16* __restrict__ hbuf_all, const f16* __restrict__ w2t_all,
                                                      const float* __restrict__ selw_all, const int* __restrict__ nsel_all,
                                                      f16* __restrict__ ye) {
  int bid = blockIdx.x;
  int wid = (bid & 7)*160 + (bid >> 3);      // 1280 blocks, XCD-chunked
  int e = wid / 160; int rem = wid - e*160;  // 160 = 20 m-blocks x 8 n-panels
  // supertile order: (mh 0..1) x (sc 0..3) x (lm 0..9) x (ln 0..1)
  int g  = rem / 20;
  int mh = g >> 2, sc = g & 3;
  int lm = (rem % 20) >> 1, ln = rem & 1;
  int m0 = (mh*10 + lm) * 128;
  int n0 = (sc*2 + ln) * 128;
  int nsel = nsel_all[e];
  if (m0 >= nsel) return;
  const f16* hb  = hbuf_all + (size_t)e*CAP*HDIM;
  const f16* w2t = w2t_all + (size_t)e*DMODEL*HDIM;

  GEMM8_PREAMBLE();

  const char* sa0 = (const char*)(hb + (size_t)(m0 + srow)*HDIM) + swz;
  const char* sa1 = (const char*)(hb + (size_t)(m0 + 64 + srow)*HDIM) + swz;
  const char* sb0 = (const char*)(w2t + (size_t)(n0 + srow)*HDIM) + swz;
  const char* sb1 = (const char*)(w2t + (size_t)(n0 + 64 + srow)*HDIM) + swz;

  GEMM8_MAINLOOP(HDIM/64);

  int rowb = m0 + wr*64;
  int colb = n0 + wc*32;
  #pragma unroll
  for (int m=0;m<4;m++) {
    #pragma unroll
    for (int r=0;r<4;r++) {
      int row = rowb + m*16 + kq*4 + r;
      float wg = selw_all[e*CAP + row];
      f16* yr = ye + (size_t)(e*CAP + row)*DMODEL;
      #pragma unroll
      for (int n=0;n<2;n++) {
        int col = colb + n*16 + fr;
        yr[col] = (f16)(acc[m][n][r] * wg);
      }
    }
  }
}

// ---------------- launch ----------------
extern "C" void kernel_launch(void* const* d_in, const int* in_sizes, int n_in,
                              void* d_out, int out_size, void* d_ws, size_t ws_size,
                              hipStream_t stream) {
  const float* x  = (const float*)d_in[0];
  const float* Wg = (const float*)d_in[1];
  const float* W1 = (const float*)d_in[2];
  const float* W2 = (const float*)d_in[3];
  float* out = (float*)d_out;

  char* ws = (char*)d_ws;
  f16*   xf16  = (f16*)(ws + XF16_OFF);
  float* probs = (float*)(ws + PROBS_OFF);
  int*   tki   = (int*)(ws + TOPKI_OFF);
  float* tkv   = (float*)(ws + TOPKV_OFF);
  int*   listt = (int*)(ws + LISTT_OFF);
  float* listw = (float*)(ws + LISTW_OFF);
  int*   listf = (int*)(ws + LISTF_OFF);
  int*   selt  = (int*)(ws + SELT_OFF);
  float* selw  = (float*)(ws + SELW_OFF);
  float* imp   = (float*)(ws + IMP_OFF);
  int*   cnt   = (int*)(ws + CNT_OFF);
  int*   nsel  = (int*)(ws + NSEL_OFF);
  f16*   w1t_all = (f16*)(ws + W1TA_OFF);
  f16*   w2t_all = (f16*)(ws + W2TA_OFF);
  f16*   hbuf_all = (f16*)(ws + HA_OFF);
  f16*   ye    = (f16*)(ws + YE_OFF);
  int*   tokmap = (int*)(ws + TOKMAP_OFF);
  const char* zbuf = ws + ZERO_OFF;

  hipMemsetAsync(ws, 0, 8192, stream);

  cvt_x_kernel<<<(S_TOK*DMODEL/8)/256, 256, 0, stream>>>(x, xf16);
  gate_kernel<<<S_TOK/4, 256, 0, stream>>>(x, Wg, probs, tki, tkv);
  imp_kernel<<<NEXP, 256, 0, stream>>>(probs, imp);
  compact_kernel<<<SK/256, 256, 0, stream>>>(tki, tkv, cnt, listt, listw, listf);
  select_kernel<<<NEXP, 1024, 0, stream>>>(listt, listw, listf, cnt, selt, selw, nsel);
  aux_kernel<<<1, 64, 0, stream>>>(imp, cnt, out + (size_t)S_TOK*DMODEL);
  // listf is dead now; reuse as tokmap
  hipMemsetAsync(tokmap, 0xFF, (size_t)SK*sizeof(int), stream);
  buildmap_kernel<<<NEXP*CAP/256, 256, 0, stream>>>(selt, tki, tokmap);

  tcvt_kernel<<<dim3(HDIM/32, DMODEL/32, NEXP), dim3(32,8), 0, stream>>>(W1, w1t_all, DMODEL, HDIM);
  tcvt_kernel<<<dim3(DMODEL/32, HDIM/32, NEXP), dim3(32,8), 0, stream>>>(W2, w2t_all, HDIM, DMODEL);
  gemm1_fused<<<NEXP*640, 512, 0, stream>>>(xf16, w1t_all, selt, nsel, hbuf_all, zbuf);
  gemm2_fused<<<NEXP*160, 512, 0, stream>>>(hbuf_all, w2t_all, selw, nsel, ye);
  combine2_kernel<<<S_TOK, 256, 0, stream>>>(ye, tokmap, out);
}

// Round 9
// 628.086 us; speedup vs baseline: 1.3371x; 1.3371x over previous
//
#include <hip/hip_runtime.h>
#include <hip/hip_fp16.h>
#include <math.h>

#define S_TOK 8192
#define DMODEL 1024
#define HDIM 4096
#define NEXP 8
#define KTOP2 2
#define CAP 2560
#define SK (S_TOK*KTOP2)

typedef _Float16 f16;
typedef _Float16 f16x8 __attribute__((ext_vector_type(8)));
typedef float f32x4 __attribute__((ext_vector_type(4)));

typedef const __attribute__((address_space(1))) void* gas_cp;
typedef __attribute__((address_space(3))) void* las_p;

__device__ __forceinline__ void gload16(const void* g, void* l) {
  __builtin_amdgcn_global_load_lds((gas_cp)g, (las_p)l, 16, 0, 0);
}

// ---------------- ws layout (bytes) ----------------
static const size_t ZERO_OFF  = 0;          // 4096 zeroed every call
static const size_t IMP_OFF   = 4096;
static const size_t CNT_OFF   = 4160;
static const size_t NSEL_OFF  = 4224;
static const size_t PROBS_OFF = 8192;
static const size_t TOPKI_OFF = 270336;
static const size_t TOPKV_OFF = 335872;
static const size_t LISTT_OFF = 401408;
static const size_t LISTW_OFF = 663552;
static const size_t LISTF_OFF = 925696;     // dead after select -> reused for tokmap
static const size_t SELT_OFF  = 1187840;
static const size_t SELW_OFF  = 1269760;
static const size_t XF16_OFF  = 1351680;                                  // S*D f16 = 16MB
static const size_t W1TA_OFF  = 18128896;                                 // 8*H*D f16 = 64MB
static const size_t W2TA_OFF  = W1TA_OFF + (size_t)NEXP*HDIM*DMODEL*2;
static const size_t HA_OFF    = W2TA_OFF + (size_t)NEXP*DMODEL*HDIM*2;    // 8*CAP*H f16 = 160MB
static const size_t YE_OFF    = XF16_OFF;   // 40MB aliased over xf16/w1t (dead by gemm2)
static const size_t TOKMAP_OFF = LISTF_OFF;

// ---------------- fast erf-based gelu (A&S 7.1.26, |err|<1.5e-7) ----------------
__device__ __forceinline__ float fast_gelu(float v) {
  float av = fabsf(v);
  float z  = av * 0.70710678118654752f;
  float tt = __builtin_amdgcn_rcpf(1.0f + 0.3275911f*z);
  float poly = tt*(0.254829592f + tt*(-0.284496736f + tt*(1.421413741f + tt*(-1.453152027f + tt*1.061405429f))));
  float ee = 1.0f - poly*__expf(-z*z);       // erf(z) for z>=0
  return 0.5f*(v + v*copysignf(ee, v));      // 0.5*v*(1+erf(v/sqrt2))
}

// ---------------- x -> f16 ----------------
__global__ __launch_bounds__(256) void cvt_x_kernel(const float* __restrict__ x, f16* __restrict__ xf) {
  size_t i = (size_t)blockIdx.x*256 + threadIdx.x;
  const float4* xv = (const float4*)x;
  float4 a = xv[2*i], b = xv[2*i+1];
  union { f16 h[8]; uint4 u; } p;
  p.h[0]=(f16)a.x; p.h[1]=(f16)a.y; p.h[2]=(f16)a.z; p.h[3]=(f16)a.w;
  p.h[4]=(f16)b.x; p.h[5]=(f16)b.y; p.h[6]=(f16)b.z; p.h[7]=(f16)b.w;
  ((uint4*)xf)[i] = p.u;
}

// ---------------- gate ----------------
__global__ __launch_bounds__(256) void gate_kernel(const float* __restrict__ x, const float* __restrict__ Wg,
                                                   float* __restrict__ probs, int* __restrict__ tki,
                                                   float* __restrict__ tkv) {
  int lane = threadIdx.x & 63;
  int t = blockIdx.x*4 + (threadIdx.x >> 6);
  const float* xr = x + (size_t)t*DMODEL;
  float p[NEXP];
  #pragma unroll
  for (int e=0;e<NEXP;e++) p[e] = 0.f;
  for (int d = lane; d < DMODEL; d += 64) {
    float xv = xr[d];
    const float4* wg = (const float4*)(Wg + d*NEXP);
    float4 w0 = wg[0], w1 = wg[1];
    p[0] += xv*w0.x; p[1] += xv*w0.y; p[2] += xv*w0.z; p[3] += xv*w0.w;
    p[4] += xv*w1.x; p[5] += xv*w1.y; p[6] += xv*w1.z; p[7] += xv*w1.w;
  }
  #pragma unroll
  for (int off=32; off; off>>=1) {
    #pragma unroll
    for (int e=0;e<NEXP;e++) p[e] += __shfl_xor(p[e], off);
  }
  float mx = p[0];
  #pragma unroll
  for (int e=1;e<NEXP;e++) mx = fmaxf(mx, p[e]);
  float sum = 0.f;
  #pragma unroll
  for (int e=0;e<NEXP;e++) { p[e] = expf(p[e]-mx); sum += p[e]; }
  float inv = 1.f/sum;
  #pragma unroll
  for (int e=0;e<NEXP;e++) p[e] *= inv;
  if (lane == 0) {
    ((float4*)(probs + t*NEXP))[0] = make_float4(p[0],p[1],p[2],p[3]);
    ((float4*)(probs + t*NEXP))[1] = make_float4(p[4],p[5],p[6],p[7]);
    int i1 = 0; float v1 = p[0];
    #pragma unroll
    for (int e=1;e<NEXP;e++) if (p[e] > v1) { v1 = p[e]; i1 = e; }
    int i2 = -1; float v2 = -1.f;
    #pragma unroll
    for (int e=0;e<NEXP;e++) if (e != i1 && p[e] > v2) { v2 = p[e]; i2 = e; }
    tki[t*2] = i1; tki[t*2+1] = i2;
    tkv[t*2] = v1; tkv[t*2+1] = v2;
  }
}

// ---------------- importance ----------------
__global__ __launch_bounds__(256) void imp_kernel(const float* __restrict__ probs, float* __restrict__ imp) {
  int e = blockIdx.x;
  float s = 0.f;
  for (int t = threadIdx.x; t < S_TOK; t += 256) s += probs[t*NEXP + e];
  #pragma unroll
  for (int off=32; off; off>>=1) s += __shfl_xor(s, off);
  __shared__ float red[4];
  if ((threadIdx.x & 63) == 0) red[threadIdx.x>>6] = s;
  __syncthreads();
  if (threadIdx.x == 0) imp[e] = red[0]+red[1]+red[2]+red[3];
}

// ---------------- compact ----------------
__global__ __launch_bounds__(256) void compact_kernel(const int* __restrict__ tki, const float* __restrict__ tkv,
                                                      int* __restrict__ cnt, int* __restrict__ listt,
                                                      float* __restrict__ listw, int* __restrict__ listf) {
  int i = blockIdx.x*256 + threadIdx.x;
  int e = tki[i];
  int p = atomicAdd(&cnt[e], 1);
  listt[e*S_TOK + p] = i >> 1;
  listw[e*S_TOK + p] = tkv[i];
  listf[e*S_TOK + p] = i;
}

// ---------------- capacity selection ----------------
__global__ __launch_bounds__(1024) void select_kernel(const int* __restrict__ listt, const float* __restrict__ listw,
                                                      const int* __restrict__ listf, const int* __restrict__ cnt,
                                                      int* __restrict__ selt, float* __restrict__ selw,
                                                      int* __restrict__ nsel) {
  __shared__ float kw[8192];
  __shared__ unsigned short kf[8192];
  int e = blockIdx.x;
  int n = cnt[e];
  const int* lt = listt + e*S_TOK; const float* lw = listw + e*S_TOK; const int* lf = listf + e*S_TOK;
  int* st = selt + e*CAP; float* sw = selw + e*CAP;
  if (threadIdx.x == 0) nsel[e] = (n < CAP) ? n : CAP;
  if (n <= CAP) {
    for (int i = threadIdx.x; i < CAP; i += 1024) {
      if (i < n) { st[i] = lt[i]; sw[i] = lw[i]; }
      else       { st[i] = -1;    sw[i] = 0.f;  }
    }
  } else {
    for (int i = threadIdx.x; i < n; i += 1024) { kw[i] = lw[i]; kf[i] = (unsigned short)lf[i]; }
    __syncthreads();
    for (int i = threadIdx.x; i < n; i += 1024) {
      float wi = kw[i]; int fi = kf[i];
      int rank = 0;
      for (int j = 0; j < n; ++j) {
        float wj = kw[j];
        rank += (wj > wi) || (wj == wi && (int)kf[j] < fi);
      }
      if (rank < CAP) { st[rank] = lt[i]; sw[rank] = wi; }
    }
  }
}

// ---------------- aux loss ----------------
__global__ void aux_kernel(const float* __restrict__ imp, const int* __restrict__ cnt, float* __restrict__ aux_out) {
  if (threadIdx.x == 0 && blockIdx.x == 0) {
    float a = 0.f;
    #pragma unroll
    for (int e=0;e<NEXP;e++) a += imp[e] * (float)cnt[e];
    *aux_out = a * (8.0f / 67108864.0f);
  }
}

// ---------------- tokmap: token -> (expert,slot) pairs ----------------
__global__ __launch_bounds__(256) void buildmap_kernel(const int* __restrict__ selt, const int* __restrict__ tki,
                                                       int* __restrict__ tokmap) {
  int i = blockIdx.x*256 + threadIdx.x;       // 0 .. E*CAP
  int t = selt[i];
  if (t >= 0) {
    int e = i / CAP;
    int k = (tki[2*t] == e) ? 0 : 1;
    tokmap[2*t + k] = i;
  }
}

// ---------------- combine: out[t] = ye[i0] + ye[i1]  (weights already applied) ----------------
__global__ __launch_bounds__(256) void combine2_kernel(const f16* __restrict__ ye, const int* __restrict__ tokmap,
                                                       float* __restrict__ out) {
  int t = blockIdx.x;
  int c = threadIdx.x * 4;
  int i0 = tokmap[2*t], i1 = tokmap[2*t+1];
  float4 o = {0.f, 0.f, 0.f, 0.f};
  if (i0 >= 0) {
    union { short4 s; f16 h[4]; } v;
    v.s = *(const short4*)(ye + (size_t)i0*DMODEL + c);
    o.x += (float)v.h[0]; o.y += (float)v.h[1]; o.z += (float)v.h[2]; o.w += (float)v.h[3];
  }
  if (i1 >= 0) {
    union { short4 s; f16 h[4]; } v;
    v.s = *(const short4*)(ye + (size_t)i1*DMODEL + c);
    o.x += (float)v.h[0]; o.y += (float)v.h[1]; o.z += (float)v.h[2]; o.w += (float)v.h[3];
  }
  *(float4*)(out + (size_t)t*DMODEL + c) = o;
}

// ---------------- transpose + cvt ----------------
__global__ __launch_bounds__(256) void tcvt_kernel(const float* __restrict__ src0, f16* __restrict__ dst0,
                                                   int R, int C) {
  __shared__ float tile[32][33];
  const float* src = src0 + (size_t)blockIdx.z*R*C;
  f16* dst = dst0 + (size_t)blockIdx.z*R*C;
  int tx = threadIdx.x, ty = threadIdx.y;
  int c0 = blockIdx.x*32, r0 = blockIdx.y*32;
  #pragma unroll
  for (int j=0;j<4;j++)
    tile[ty + 8*j][tx] = src[(size_t)(r0 + ty + 8*j)*C + c0 + tx];
  __syncthreads();
  #pragma unroll
  for (int j=0;j<4;j++)
    dst[(size_t)(c0 + ty + 8*j)*R + r0 + tx] = (f16)tile[tx][ty + 8*j];
}

// ================= GEMM bodies: depth-3 counted-vmcnt, 2 blocks/CU =================
// BM=256, BN=128, BK=32, 8 waves x (64x64 wave tile; acc = 16 f32x4 = 64 AGPR,
// ~119 unified regs < 128 -> 4 waves/SIMD). 3 buffers x (16KB A + 8KB B) = 72KB
// -> 2 blocks/CU (16 waves/CU, the measured sweet spot r4-r8).
// Per K-step: VMW(3) waits ONLY buf kt's 3 loads (buf kt+1's stay in flight -
// T4 counted vmcnt, m218); s_barrier; STAGE buf kt+2 issued AFTER the barrier
// (its region's reads completed before every wave's barrier arrival: ds_read ->
// MFMA data deps force completion pre-barrier -> race-free); 8 ds_read_b128;
// setprio(1) 16 MFMA setprio(0). ONE barrier per K-step, never vmcnt(0) in
// steady state. Row = 64B = 4 16B-slots; swizzle phys = ((s^(r&3))+((r>>2)&3))&3
// -> <=2-way bank aliasing (free, m136). Source pre-swizzled (both-sides, m173).

#define BAR() asm volatile("s_barrier" ::: "memory")
#define VMW(n) asm volatile("s_waitcnt vmcnt(" #n ")" ::: "memory")

#define GEMM9_PREAMBLE() \
  __shared__ __align__(16) f16 As[3][256*32]; \
  __shared__ __align__(16) f16 Bs[3][128*32]; \
  int tid = threadIdx.x; \
  int l = tid & 63; \
  int w = tid >> 6; \
  int wr = w >> 1, wc = w & 1; \
  int fr = l & 15, kq = l >> 4; \
  int srow = tid >> 2; \
  int pslot = tid & 3; \
  int lslot = ((pslot - ((srow>>2)&3)) & 3) ^ (srow&3); \
  int swz = lslot*16; \
  int aoff[4], boff[4]; \
  _Pragma("unroll") for (int m=0;m<4;m++) { int r = wr*64 + m*16 + fr; \
    aoff[m] = r*64 + (((((kq) ^ (r&3)) + ((r>>2)&3)) & 3) * 16); } \
  _Pragma("unroll") for (int n=0;n<4;n++) { int r = wc*64 + n*16 + fr; \
    boff[n] = r*64 + (((((kq) ^ (r&3)) + ((r>>2)&3)) & 3) * 16); } \
  f32x4 acc[4][4]; \
  _Pragma("unroll") for (int m=0;m<4;m++) _Pragma("unroll") for (int n=0;n<4;n++) \
    acc[m][n] = (f32x4){0.f,0.f,0.f,0.f};

#define GEMM9_STAGE(Ad, Bd, kt) { int ko = (kt)*64; \
    gload16(sa0 + ko, Ad + tid*16); \
    gload16(sa1 + ko, Ad + 8192 + tid*16); \
    gload16(sb0 + ko, Bd + tid*16); }

#define GEMM9_MAINLOOP(KT) { \
  char* A0 = (char*)&As[0][0]; char* A1 = (char*)&As[1][0]; char* A2 = (char*)&As[2][0]; \
  char* B0 = (char*)&Bs[0][0]; char* B1 = (char*)&Bs[1][0]; char* B2 = (char*)&Bs[2][0]; \
  GEMM9_STAGE(A0, B0, 0); \
  GEMM9_STAGE(A1, B1, 1); \
  for (int kt = 0; kt < (KT); ++kt) { \
    if (kt + 1 < (KT)) { VMW(3); } else { VMW(0); } \
    BAR(); \
    if (kt + 2 < (KT)) GEMM9_STAGE(A2, B2, kt+2); \
    f16x8 af[4], bf[4]; \
    _Pragma("unroll") for (int m=0;m<4;m++) af[m] = *(const f16x8*)(A0 + aoff[m]); \
    _Pragma("unroll") for (int n=0;n<4;n++) bf[n] = *(const f16x8*)(B0 + boff[n]); \
    __builtin_amdgcn_s_setprio(1); \
    _Pragma("unroll") for (int m=0;m<4;m++) \
      _Pragma("unroll") for (int n=0;n<4;n++) \
        acc[m][n] = __builtin_amdgcn_mfma_f32_16x16x32_f16(af[m], bf[n], acc[m][n], 0, 0, 0); \
    __builtin_amdgcn_s_setprio(0); \
    char* t0 = A0; A0 = A1; A1 = A2; A2 = t0; \
    char* t1 = B0; B0 = B1; B1 = B2; B2 = t1; \
  } }

// ---------------- GEMM1 fused over experts ----------------
__global__ __launch_bounds__(512, 4) void gemm1_fused(const f16* __restrict__ xf, const f16* __restrict__ w1t_all,
                                                      const int* __restrict__ selt_all, const int* __restrict__ nsel_all,
                                                      f16* __restrict__ hbuf_all, const char* __restrict__ zbuf) {
  int bid = blockIdx.x;
  int wid = (bid & 7)*320 + (bid >> 3);      // XCD-chunked: each XCD = one expert
  int e = wid / 320; int rem = wid - e*320;  // 320 = 10 m-blocks(256) x 32 n-panels(128)
  // supertile order: (sc 0..15) x (lm 0..9) x (ln 0..1)
  int g  = rem / 20;
  int lm = (rem % 20) >> 1, ln = rem & 1;
  int m0 = lm * 256;
  int n0 = (g*2 + ln) * 128;
  int nsel = nsel_all[e];
  if (m0 >= nsel) return;
  const int* selt = selt_all + e*CAP;
  const f16* w1t = w1t_all + (size_t)e*HDIM*DMODEL;
  f16* hbuf = hbuf_all + (size_t)e*CAP*HDIM;

  GEMM9_PREAMBLE();

  const char *sa0, *sa1;
  {
    int t0 = selt[m0 + srow];
    int t1 = selt[m0 + 128 + srow];
    sa0 = ((t0 >= 0) ? (const char*)(xf + (size_t)t0*DMODEL) : zbuf) + swz;
    sa1 = ((t1 >= 0) ? (const char*)(xf + (size_t)t1*DMODEL) : zbuf) + swz;
  }
  const char* sb0 = (const char*)(w1t + (size_t)(n0 + srow)*DMODEL) + swz;

  GEMM9_MAINLOOP(DMODEL/32);

  int rowb = m0 + wr*64;
  int colb = n0 + wc*64;
  #pragma unroll
  for (int m=0;m<4;m++) {
    #pragma unroll
    for (int n=0;n<4;n++) {
      #pragma unroll
      for (int r=0;r<4;r++) {
        int row = rowb + m*16 + kq*4 + r;
        int col = colb + n*16 + fr;
        hbuf[(size_t)row*HDIM + col] = (f16)fast_gelu(acc[m][n][r]);
      }
    }
  }
}

// ---------------- GEMM2 fused: ye[e,row] = wg * (h @ W2T), no atomics ----------------
__global__ __launch_bounds__(512, 4) void gemm2_fused(const f16* __restrict__ hbuf_all, const f16* __restrict__ w2t_all,
                                                      const float* __restrict__ selw_all, const int* __restrict__ nsel_all,
                                                      f16* __restrict__ ye) {
  int bid = blockIdx.x;
  int wid = (bid & 7)*80 + (bid >> 3);       // 640 blocks, XCD-chunked
  int e = wid / 80; int rem = wid - e*80;    // 80 = 10 m-blocks(256) x 8 n-panels(128)
  int g  = rem / 20;
  int lm = (rem % 20) >> 1, ln = rem & 1;
  int m0 = lm * 256;
  int n0 = (g*2 + ln) * 128;
  int nsel = nsel_all[e];
  if (m0 >= nsel) return;
  const f16* hb  = hbuf_all + (size_t)e*CAP*HDIM;
  const f16* w2t = w2t_all + (size_t)e*DMODEL*HDIM;

  GEMM9_PREAMBLE();

  const char* sa0 = (const char*)(hb + (size_t)(m0 + srow)*HDIM) + swz;
  const char* sa1 = (const char*)(hb + (size_t)(m0 + 128 + srow)*HDIM) + swz;
  const char* sb0 = (const char*)(w2t + (size_t)(n0 + srow)*HDIM) + swz;

  GEMM9_MAINLOOP(HDIM/32);

  int rowb = m0 + wr*64;
  int colb = n0 + wc*64;
  #pragma unroll
  for (int m=0;m<4;m++) {
    #pragma unroll
    for (int r=0;r<4;r++) {
      int row = rowb + m*16 + kq*4 + r;
      float wg = selw_all[e*CAP + row];
      f16* yr = ye + (size_t)(e*CAP + row)*DMODEL;
      #pragma unroll
      for (int n=0;n<4;n++) {
        int col = colb + n*16 + fr;
        yr[col] = (f16)(acc[m][n][r] * wg);
      }
    }
  }
}

// ---------------- launch ----------------
extern "C" void kernel_launch(void* const* d_in, const int* in_sizes, int n_in,
                              void* d_out, int out_size, void* d_ws, size_t ws_size,
                              hipStream_t stream) {
  const float* x  = (const float*)d_in[0];
  const float* Wg = (const float*)d_in[1];
  const float* W1 = (const float*)d_in[2];
  const float* W2 = (const float*)d_in[3];
  float* out = (float*)d_out;

  char* ws = (char*)d_ws;
  f16*   xf16  = (f16*)(ws + XF16_OFF);
  float* probs = (float*)(ws + PROBS_OFF);
  int*   tki   = (int*)(ws + TOPKI_OFF);
  float* tkv   = (float*)(ws + TOPKV_OFF);
  int*   listt = (int*)(ws + LISTT_OFF);
  float* listw = (float*)(ws + LISTW_OFF);
  int*   listf = (int*)(ws + LISTF_OFF);
  int*   selt  = (int*)(ws + SELT_OFF);
  float* selw  = (float*)(ws + SELW_OFF);
  float* imp   = (float*)(ws + IMP_OFF);
  int*   cnt   = (int*)(ws + CNT_OFF);
  int*   nsel  = (int*)(ws + NSEL_OFF);
  f16*   w1t_all = (f16*)(ws + W1TA_OFF);
  f16*   w2t_all = (f16*)(ws + W2TA_OFF);
  f16*   hbuf_all = (f16*)(ws + HA_OFF);
  f16*   ye    = (f16*)(ws + YE_OFF);
  int*   tokmap = (int*)(ws + TOKMAP_OFF);
  const char* zbuf = ws + ZERO_OFF;

  hipMemsetAsync(ws, 0, 8192, stream);

  cvt_x_kernel<<<(S_TOK*DMODEL/8)/256, 256, 0, stream>>>(x, xf16);
  gate_kernel<<<S_TOK/4, 256, 0, stream>>>(x, Wg, probs, tki, tkv);
  imp_kernel<<<NEXP, 256, 0, stream>>>(probs, imp);
  compact_kernel<<<SK/256, 256, 0, stream>>>(tki, tkv, cnt, listt, listw, listf);
  select_kernel<<<NEXP, 1024, 0, stream>>>(listt, listw, listf, cnt, selt, selw, nsel);
  aux_kernel<<<1, 64, 0, stream>>>(imp, cnt, out + (size_t)S_TOK*DMODEL);
  // listf is dead now; reuse as tokmap
  hipMemsetAsync(tokmap, 0xFF, (size_t)SK*sizeof(int), stream);
  buildmap_kernel<<<NEXP*CAP/256, 256, 0, stream>>>(selt, tki, tokmap);

  tcvt_kernel<<<dim3(HDIM/32, DMODEL/32, NEXP), dim3(32,8), 0, stream>>>(W1, w1t_all, DMODEL, HDIM);
  tcvt_kernel<<<dim3(DMODEL/32, HDIM/32, NEXP), dim3(32,8), 0, stream>>>(W2, w2t_all, HDIM, DMODEL);
  gemm1_fused<<<NEXP*320, 512, 0, stream>>>(xf16, w1t_all, selt, nsel, hbuf_all, zbuf);
  gemm2_fused<<<NEXP*80, 512, 0, stream>>>(hbuf_all, w2t_all, selw, nsel, ye);
  combine2_kernel<<<S_TOK, 256, 0, stream>>>(ye, tokmap, out);
}